// Round 1
// baseline (175.449 us; speedup 1.0000x reference)
//
#include <hip/hip_runtime.h>

// SparseGrid gather: out[i, 18] = embeddings[t_idx[i], x_idx[i]+{-1,0,1}, y_idx[i]+{-1,0,1}, :2]
// embeddings: (600, 300, 300, 2) fp32, row-major. inputs: (N, 3) fp32 in [0,1).

#define T_RES 600
#define X_RES 300
#define Y_RES 300

__global__ __launch_bounds__(256) void sparsegrid_gather(
    const float* __restrict__ inputs,
    const float* __restrict__ emb,
    float* __restrict__ out,
    int n)
{
    int i = blockIdx.x * blockDim.x + threadIdx.x;
    if (i >= n) return;

    float t = inputs[3 * i + 0];
    float x = inputs[3 * i + 1];
    float y = inputs[3 * i + 2];

    // Match numpy fp32 exactly: separate mul + add, round-to-nearest, NO fma.
    int ti = (int)__fadd_rn(__fmul_rn((float)(T_RES - 1), t), 0.5f);
    int xi = (int)__fadd_rn(__fmul_rn((float)(X_RES - 1), x), 0.5f);
    int yi = (int)__fadd_rn(__fmul_rn((float)(Y_RES - 1), y), 0.5f);
    ti = min(max(ti, 0), T_RES - 1);
    xi = min(max(xi, 0), X_RES - 1);
    yi = min(max(yi, 0), Y_RES - 1);

    int xs0 = max(xi - 1, 0), xs1 = xi, xs2 = min(xi + 1, X_RES - 1);
    int ys0 = max(yi - 1, 0), ys1 = yi, ys2 = min(yi + 1, Y_RES - 1);

    // float2 granularity: element (t,x,y) is float2 #((t*X_RES + x)*Y_RES + y)
    const float2* __restrict__ e2 = (const float2*)emb;
    float2* __restrict__ o2 = (float2*)(out + (size_t)i * 18);

    int tb = ti * X_RES;
    int r0 = (tb + xs0) * Y_RES;
    int r1 = (tb + xs1) * Y_RES;
    int r2 = (tb + xs2) * Y_RES;

    o2[0] = e2[r0 + ys0];
    o2[1] = e2[r0 + ys1];
    o2[2] = e2[r0 + ys2];
    o2[3] = e2[r1 + ys0];
    o2[4] = e2[r1 + ys1];
    o2[5] = e2[r1 + ys2];
    o2[6] = e2[r2 + ys0];
    o2[7] = e2[r2 + ys1];
    o2[8] = e2[r2 + ys2];
}

extern "C" void kernel_launch(void* const* d_in, const int* in_sizes, int n_in,
                              void* d_out, int out_size, void* d_ws, size_t ws_size,
                              hipStream_t stream) {
    const float* inputs = (const float*)d_in[0];
    const float* emb    = (const float*)d_in[1];
    float* out          = (float*)d_out;

    int n = in_sizes[0] / 3;  // N_POINTS
    int block = 256;
    int grid = (n + block - 1) / block;
    sparsegrid_gather<<<grid, block, 0, stream>>>(inputs, emb, out, n);
}

// Round 2
// 155.323 us; speedup vs baseline: 1.1296x; 1.1296x over previous
//
#include <hip/hip_runtime.h>

// SparseGrid gather: out[i, 18] = embeddings[t_idx[i], x_idx[i]+{-1,0,1}, y_idx[i]+{-1,0,1}, :2]
// embeddings: (600, 300, 300, 2) fp32, row-major. inputs: (N, 3) fp32 in [0,1).
//
// Round 2: LDS-staged coalesced output writes. Each block's 256 points own a
// contiguous 18432-B output slab; stage per-thread 18 floats in LDS (stride-19
// rows, 19 coprime 32 -> bank-conflict-free), then write lane-consecutive
// float2s (ideal 72 lines/wave instead of ~576 scattered).

#define T_RES 600
#define X_RES 300
#define Y_RES 300
#define BLK 256

__global__ __launch_bounds__(BLK) void sparsegrid_gather(
    const float* __restrict__ inputs,
    const float* __restrict__ emb,
    float* __restrict__ out,
    int n)
{
    __shared__ float lds[BLK * 19];

    int tid  = threadIdx.x;
    int base = blockIdx.x * BLK;
    int i    = base + tid;
    int npts = n - base;             // points in this block (may exceed BLK; clamp below)
    if (npts > BLK) npts = BLK;

    if (tid < npts) {
        float t = inputs[3 * i + 0];
        float x = inputs[3 * i + 1];
        float y = inputs[3 * i + 2];

        // Match numpy fp32 exactly: separate mul + add, round-to-nearest, NO fma.
        int ti = (int)__fadd_rn(__fmul_rn((float)(T_RES - 1), t), 0.5f);
        int xi = (int)__fadd_rn(__fmul_rn((float)(X_RES - 1), x), 0.5f);
        int yi = (int)__fadd_rn(__fmul_rn((float)(Y_RES - 1), y), 0.5f);
        ti = min(max(ti, 0), T_RES - 1);
        xi = min(max(xi, 0), X_RES - 1);
        yi = min(max(yi, 0), Y_RES - 1);

        int xs0 = max(xi - 1, 0), xs2 = min(xi + 1, X_RES - 1);
        int ys0 = max(yi - 1, 0), ys1 = yi, ys2 = min(yi + 1, Y_RES - 1);

        const float2* __restrict__ e2 = (const float2*)emb;
        int tb = ti * X_RES;
        int r0 = (tb + xs0) * Y_RES;
        int r1 = (tb + xi ) * Y_RES;
        int r2 = (tb + xs2) * Y_RES;

        float2 v0 = e2[r0 + ys0];
        float2 v1 = e2[r0 + ys1];
        float2 v2 = e2[r0 + ys2];
        float2 v3 = e2[r1 + ys0];
        float2 v4 = e2[r1 + ys1];
        float2 v5 = e2[r1 + ys2];
        float2 v6 = e2[r2 + ys0];
        float2 v7 = e2[r2 + ys1];
        float2 v8 = e2[r2 + ys2];

        float* row = &lds[tid * 19];
        row[0]  = v0.x; row[1]  = v0.y;
        row[2]  = v1.x; row[3]  = v1.y;
        row[4]  = v2.x; row[5]  = v2.y;
        row[6]  = v3.x; row[7]  = v3.y;
        row[8]  = v4.x; row[9]  = v4.y;
        row[10] = v5.x; row[11] = v5.y;
        row[12] = v6.x; row[13] = v6.y;
        row[14] = v7.x; row[15] = v7.y;
        row[16] = v8.x; row[17] = v8.y;
    }

    __syncthreads();

    // Coalesced write of the block's slab: npts*9 float2s, lane-consecutive.
    int total2 = npts * 9;
    float2* oblk = (float2*)(out + (size_t)base * 18);
    #pragma unroll
    for (int k = 0; k < 9; ++k) {
        int d2 = tid + BLK * k;          // float2 index within slab
        if (d2 < total2) {
            int p = d2 / 9;              // point (magic-mul division)
            int e = d2 - p * 9;          // float2 slot within point
            float2 w;
            w.x = lds[p * 19 + 2 * e];
            w.y = lds[p * 19 + 2 * e + 1];
            oblk[d2] = w;
        }
    }
}

extern "C" void kernel_launch(void* const* d_in, const int* in_sizes, int n_in,
                              void* d_out, int out_size, void* d_ws, size_t ws_size,
                              hipStream_t stream) {
    const float* inputs = (const float*)d_in[0];
    const float* emb    = (const float*)d_in[1];
    float* out          = (float*)d_out;

    int n = in_sizes[0] / 3;  // N_POINTS
    int grid = (n + BLK - 1) / BLK;
    sparsegrid_gather<<<grid, BLK, 0, stream>>>(inputs, emb, out, n);
}